// Round 12
// baseline (196.960 us; speedup 1.0000x reference)
//
#include <hip/hip_runtime.h>
#include <hip/hip_bf16.h>
#include <math.h>

#pragma clang fp contract(off)

#define NRES 768
#define FIN 316
#define DPAIR 128
#define NCHUNK 9216   // 768*768/64 pairs per chunk of 64
#define NBLOCK 512
#define NTHREAD 512
#define NWAVES (NBLOCK * (NTHREAD/64))

typedef unsigned int u32;
typedef unsigned short u16;

// f32 div/sqrt via f64: correctly rounded
__device__ __forceinline__ float f32div(float a, float b){ return (float)((double)a / (double)b); }
__device__ __forceinline__ float f32sqrt(float a){ return (float)sqrt((double)a); }

struct V3 { float x, y, z; };

__device__ __forceinline__ V3 vsub(const V3 a, const V3 b){
  V3 r; r.x = a.x - b.x; r.y = a.y - b.y; r.z = a.z - b.z; return r;
}
__device__ __forceinline__ V3 vcross(const V3 a, const V3 b){
  V3 r;
  r.x = a.y*b.z - a.z*b.y;
  r.y = a.z*b.x - a.x*b.z;
  r.z = a.x*b.y - a.y*b.x;
  return r;
}
// init-0 reduce (C-family verified): 0+e0+e1+e2 — numerically == left-assoc sum,
// differing ONLY in -0 normalization (gold's diagonal is uniformly +0 / bin 10).
__device__ __forceinline__ float vdot(const V3 a, const V3 b){
  float s = 0.0f + a.x*b.x;
  s = s + a.y*b.y;
  s = s + a.z*b.z;
  return s;
}
__device__ __forceinline__ float sumsq3(float x, float y, float z){
  float s = 0.0f + x*x;
  s = s + y*y;
  s = s + z*z;
  return s;
}
__device__ __forceinline__ V3 vnorm(const V3 v){
  float ss = sumsq3(v.x, v.y, v.z) + 1e-16f;
  float r = f32sqrt(ss);
  float c = fmaxf(r, 1e-8f);
  V3 o; o.x = f32div(v.x, c); o.y = f32div(v.y, c); o.z = f32div(v.z, c); return o;
}

// Correctly-rounded f32 atan2 (gold = modern glibc CORE-MATH atan2f):
// explicit IEEE zero cases + f64-promoted atan2 rounded once to f32.
__device__ __forceinline__ float atan2_cr(float y, float x){
  if (y == 0.0f) {
    bool xneg = (__float_as_uint(x) >> 31) != 0;   // x<0 or x==-0
    float pi_f = __uint_as_float(0x40490fdb);
    if (xneg) return (__float_as_uint(y) >> 31) ? -pi_f : pi_f;
    return y;                                      // atan2(+-0, x>=+0) = +-0
  }
  if (x == 0.0f) {
    float pio2 = __uint_as_float(0x3fc90fdb);
    return (y > 0.0f) ? pio2 : -pio2;
  }
  return (float)atan2((double)y, (double)x);       // CR f32 (prob 1-2^-29/sample)
}

// numpy float64 linspace: step = (stop-start)/div FIRST (f64); lim_k = k*step+start;
// endpoint lim_19 = stop exactly. searchsorted('left') = count(lim < v), f64 compare.
__device__ __forceinline__ u32 binIdx64(double v, double step, double start, double stop){
  u32 c = 0;
#pragma unroll
  for (int k = 0; k < 19; ++k){
    double lim = (double)k * step + start;  // mul then add, contract off
    c += (lim < v) ? 1u : 0u;
  }
  c += (stop < v) ? 1u : 0u;
  return c;
}

#define PI64 3.141592653589793

__device__ u32 dihedBin(V3 a, V3 b, V3 c, V3 d, double astep){
  V3 v1 = vsub(b, a), v2 = vsub(c, b), v3 = vsub(d, c);
  V3 n1 = vnorm(vcross(v1, v2));
  V3 n2 = vnorm(vcross(v2, v3));
  V3 m  = vcross(n1, n2);
  float dt = vdot(m, v2);
  // npy_sign: +-1 nonzero, 0 for zero (init-0 sum => dt zero is always +0 anyway)
  float sg = (dt > 0.0f) ? 1.0f : ((dt < 0.0f) ? -1.0f : dt);
  float ss = sumsq3(m.x, m.y, m.z) + 1e-16f;
  float yy = sg * f32sqrt(ss);
  float xx = vdot(n1, n2);
  float th = atan2_cr(yy, xx);
  return binIdx64((double)th, astep, -PI64, PI64);
}

__device__ u32 bondBin(V3 a, V3 b, V3 c, double astep){
  V3 u = vnorm(vsub(b, a));
  V3 v = vnorm(vsub(c, a));
  V3 m = vcross(u, v);
  float ss = sumsq3(m.x, m.y, m.z) + 1e-16f;
  float yy = f32sqrt(ss);
  float xx = vdot(u, v);
  float th = atan2_cr(yy, xx);
  return binIdx64((double)th, astep, -PI64, PI64);
}

__device__ __forceinline__ float rlf(float v, int l){
  return __uint_as_float(__builtin_amdgcn_readlane(__float_as_uint(v), l));
}

// ---- kernel A: W[128][316] f32 -> Wt[316][128] bf16 (RNE) ----
__global__ void prep_kernel(const float* __restrict__ W, u16* __restrict__ Wt){
  int e = blockIdx.x * 256 + threadIdx.x;
  if (e < FIN * DPAIR) {
    int d = e / FIN;
    int f = e - d * FIN;
    u32 u = __float_as_uint(W[e]);
    u32 r = (u + 0x7fffu + ((u >> 16) & 1u)) >> 16;
    Wt[f * DPAIR + d] = (u16)r;
  }
}

__global__ __launch_bounds__(NTHREAD, 4) void pairfeat_kernel(
    const float* __restrict__ mask, const float* __restrict__ cmask,
    const float* __restrict__ cnm, const float* __restrict__ crd,
    const float* __restrict__ W, const u16* __restrict__ Wt, const int useWt,
    const float* __restrict__ bias, const float* __restrict__ gam,
    const float* __restrict__ bet, float* __restrict__ out)
{
  __shared__ u32 Wl[FIN * 64];   // [f][d] bf16 pairs packed as u32: 80,896 B

  if (useWt) {
    const u32* src = (const u32*)Wt;
    for (int e = threadIdx.x; e < FIN * 64; e += NTHREAD) Wl[e] = src[e];
  } else {
    for (int e = threadIdx.x; e < FIN * DPAIR; e += NTHREAD) {
      int d = e & 127, f = e >> 7;
      u32 u = __float_as_uint(W[d * FIN + f]);
      u32 r = (u + 0x7fffu + ((u >> 16) & 1u)) >> 16;
      ((u16*)Wl)[f * DPAIR + d] = (u16)r;
    }
  }
  __syncthreads();

  const int lane = threadIdx.x & 63;
  const int gw = (blockIdx.x * NTHREAD + threadIdx.x) >> 6;
  const int d0 = lane << 1;
  const float2 bv = *(const float2*)(bias + d0);
  const float2 gv = *(const float2*)(gam + d0);
  const float2 ev = *(const float2*)(bet + d0);

  // numpy float64 linspace bin parameters
  const double DSTEP  = (2.0 - 0.1) / 19.0;   // 0.09999999999999999167 (NOT 0.1)
  const double DSTART = 0.1, DSTOP = 2.0;
  const double ASTEP  = (PI64 + PI64) / 19.0;

  for (int ch = gw; ch < NCHUNK; ch += NWAVES) {
    const int i = ch / 12;
    const int j = (ch - i * 12) * 64 + lane;

    // ----- phase 1: per-lane pair (i, j), f32 geometry (C config) -----
    float mi = mask[i], mj = mask[j];
    float hci = cmask[i * 4 + 3], hcj = cmask[j * 4 + 3];
    float pm = mi * mj;

    const float4* jq = (const float4*)(cnm + (size_t)j * 12);
    float4 q0 = jq[0], q1 = jq[1], q2 = jq[2];
    float cax = cnm[i*12+3], cay = cnm[i*12+4], caz = cnm[i*12+5];

    // seq-sep: limits = linspace(-62.5, 62.5, 126), step exactly 1.0; half-integer
    // limits never tie integer i-j  =>  count(lim < x) = clamp(x+63, 0, 126) EXACTLY.
    int sepb = i - j + 63;
    sepb = sepb < 0 ? 0 : (sepb > 126 ? 126 : sepb);
    u32 pack0 = (u32)sepb;
    {
      float ax[4] = {q0.x, q0.w, q1.z, q2.y};
      float ay[4] = {q0.y, q1.x, q1.w, q2.z};
      float az[4] = {q0.z, q1.y, q2.x, q2.w};
      int sh = 7;
#pragma unroll
      for (int a = 0; a < 4; ++a) {
        float dx = cax - ax[a];
        float dy = cay - ay[a];
        float dz = caz - az[a];
        float ss = sumsq3(dx, dy, dz) + 1e-10f;
        float dist = f32sqrt(ss);
        pack0 |= binIdx64((double)dist, DSTEP, DSTART, DSTOP) << sh; sh += 5;
      }
    }

    const float4* jr = (const float4*)(crd + (size_t)j * 12);
    float4 r0 = jr[0], r1 = jr[1], r2 = jr[2];
    V3 Nj  = {r0.x, r0.y, r0.z};
    V3 CAj = {r0.w, r1.x, r1.y};
    V3 CBj = {r2.y, r2.z, r2.w};
    V3 Ni  = {crd[i*12+0], crd[i*12+1], crd[i*12+2]};
    V3 CAi = {crd[i*12+3], crd[i*12+4], crd[i*12+5]};
    V3 CBi = {crd[i*12+9], crd[i*12+10], crd[i*12+11]};

    u32 pack1 = 0;
    pack1 |= dihedBin(Ni, CAi, CBi, CBj, ASTEP);
    pack1 |= dihedBin(Nj, CAj, CBj, CBi, ASTEP) << 5;
    pack1 |= bondBin(CAi, CBi, CBj, ASTEP) << 10;
    pack1 |= bondBin(CAj, CBj, CBi, ASTEP) << 15;
    pack1 |= dihedBin(CAi, CBi, CBj, CAj, ASTEP) << 20;

    float pm2 = pm * pm;
    float wbb = pm2;
    float wbb3 = pm2 * hcj;
    float tw = pm * hci; tw = tw * hci; float wor = tw * pm;

    // ----- phase 2: 64 pairs, wave-wide gather + LayerNorm + store -----
    float* ob = out + (size_t)ch * (64 * DPAIR);
#pragma unroll 1
    for (int p = 0; p < 64; ++p) {
      u32 k0 = __builtin_amdgcn_readlane(pack0, p);
      u32 k1 = __builtin_amdgcn_readlane(pack1, p);
      float Pm  = rlf(pm, p);
      float Wbb = rlf(wbb, p);
      float Wb3 = rlf(wbb3, p);
      float Wor = rlf(wor, p);

      float a0 = bv.x, a1 = bv.y;
      u32 cidx[10];
      cidx[0] = (k0 & 127u);
      cidx[1] = 127u +        ((k0 >> 7)  & 31u);
      cidx[2] = 127u + 21u +  ((k0 >> 12) & 31u);
      cidx[3] = 127u + 42u +  ((k0 >> 17) & 31u);
      cidx[4] = 127u + 63u +  ((k0 >> 22) & 31u);
      cidx[5] = 211u +        (k1 & 31u);
      cidx[6] = 211u + 21u +  ((k1 >> 5)  & 31u);
      cidx[7] = 211u + 42u +  ((k1 >> 10) & 31u);
      cidx[8] = 211u + 63u +  ((k1 >> 15) & 31u);
      cidx[9] = 211u + 84u +  ((k1 >> 20) & 31u);
      float wv[10] = {Pm, Wbb, Wbb, Wbb, Wb3, Wor, Wor, Wor, Wor, Wor};
#pragma unroll
      for (int t = 0; t < 10; ++t) {
        u32 u = Wl[cidx[t] * 64 + lane];
        a0 = fmaf(wv[t], __uint_as_float(u << 16), a0);
        a1 = fmaf(wv[t], __uint_as_float(u & 0xffff0000u), a1);
      }
      float s  = a0 + a1;
      float s2 = fmaf(a0, a0, a1 * a1);
      s += __shfl_xor(s, 32); s2 += __shfl_xor(s2, 32);
      s += __shfl_xor(s, 16); s2 += __shfl_xor(s2, 16);
      s += __shfl_xor(s, 8);  s2 += __shfl_xor(s2, 8);
      s += __shfl_xor(s, 4);  s2 += __shfl_xor(s2, 4);
      s += __shfl_xor(s, 2);  s2 += __shfl_xor(s2, 2);
      s += __shfl_xor(s, 1);  s2 += __shfl_xor(s2, 1);
      float mu = s * 0.0078125f;
      float var = fmaf(s2, 0.0078125f, -(mu * mu));
      float inv = 1.0f / sqrtf(var + 1e-5f);
      float o0 = (a0 - mu) * inv; o0 = fmaf(o0, gv.x, ev.x); o0 *= Pm;
      float o1 = (a1 - mu) * inv; o1 = fmaf(o1, gv.y, ev.y); o1 *= Pm;
      float2 ov; ov.x = o0; ov.y = o1;
      *(float2*)(ob + (size_t)p * DPAIR + d0) = ov;
    }
  }
}

extern "C" void kernel_launch(void* const* d_in, const int* in_sizes, int n_in,
                              void* d_out, int out_size, void* d_ws, size_t ws_size,
                              hipStream_t stream) {
  const float* mask  = (const float*)d_in[0];
  const float* cmask = (const float*)d_in[1];
  const float* cnm   = (const float*)d_in[2];
  const float* crd   = (const float*)d_in[3];
  const float* W     = (const float*)d_in[4];
  const float* bias  = (const float*)d_in[5];
  const float* gam   = (const float*)d_in[6];
  const float* bet   = (const float*)d_in[7];
  float* out = (float*)d_out;

  const size_t wtBytes = (size_t)FIN * DPAIR * sizeof(u16);
  int useWt = (ws_size >= wtBytes) ? 1 : 0;
  u16* Wt = (u16*)d_ws;
  if (useWt) {
    prep_kernel<<<(FIN * DPAIR + 255) / 256, 256, 0, stream>>>(W, Wt);
  }
  pairfeat_kernel<<<NBLOCK, NTHREAD, 0, stream>>>(
      mask, cmask, cnm, crd, W, Wt, useWt, bias, gam, bet, out);
}

// Round 14
// 169.905 us; speedup vs baseline: 1.1592x; 1.1592x over previous
//
#include <hip/hip_runtime.h>
#include <hip/hip_bf16.h>
#include <math.h>

#pragma clang fp contract(off)

#define NRES 768
#define FIN 316
#define DPAIR 128
#define NCHUNK 9216   // 768*768/64 pairs per chunk of 64
#define NBLOCK 512
#define NTHREAD 512
#define NWAVES (NBLOCK * (NTHREAD/64))

typedef unsigned int u32;
typedef unsigned short u16;

// f32 div/sqrt via f64: correctly rounded
__device__ __forceinline__ float f32div(float a, float b){ return (float)((double)a / (double)b); }
__device__ __forceinline__ float f32sqrt(float a){ return (float)sqrt((double)a); }

struct V3 { float x, y, z; };

__device__ __forceinline__ V3 vsub(const V3 a, const V3 b){
  V3 r; r.x = a.x - b.x; r.y = a.y - b.y; r.z = a.z - b.z; return r;
}
__device__ __forceinline__ V3 vcross(const V3 a, const V3 b){
  V3 r;
  r.x = a.y*b.z - a.z*b.y;
  r.y = a.z*b.x - a.x*b.z;
  r.z = a.x*b.y - a.y*b.x;
  return r;
}
// init-0 reduce (verified): 0+e0+e1+e2 — -0 normalization matches gold's diagonal.
__device__ __forceinline__ float vdot(const V3 a, const V3 b){
  float s = 0.0f + a.x*b.x;
  s = s + a.y*b.y;
  s = s + a.z*b.z;
  return s;
}
__device__ __forceinline__ float sumsq3(float x, float y, float z){
  float s = 0.0f + x*x;
  s = s + y*y;
  s = s + z*z;
  return s;
}
__device__ __forceinline__ V3 vnorm(const V3 v){
  float ss = sumsq3(v.x, v.y, v.z) + 1e-16f;
  float r = f32sqrt(ss);
  float c = fmaxf(r, 1e-8f);
  V3 o; o.x = f32div(v.x, c); o.y = f32div(v.y, c); o.z = f32div(v.z, c); return o;
}

// CR f32 atan2 (r12-verified gold flavor): explicit IEEE zero cases + f64 promote.
__device__ __forceinline__ float atan2_cr(float y, float x){
  if (y == 0.0f) {
    bool xneg = (__float_as_uint(x) >> 31) != 0;
    float pi_f = __uint_as_float(0x40490fdb);
    if (xneg) return (__float_as_uint(y) >> 31) ? -pi_f : pi_f;
    return y;
  }
  if (x == 0.0f) {
    float pio2 = __uint_as_float(0x3fc90fdb);
    return (y > 0.0f) ? pio2 : -pio2;
  }
  return (float)atan2((double)y, (double)x);
}

// numpy float64 linspace binning (r12-verified)
__device__ __forceinline__ u32 binIdx64(double v, double step, double start, double stop){
  u32 c = 0;
#pragma unroll
  for (int k = 0; k < 19; ++k){
    double lim = (double)k * step + start;
    c += (lim < v) ? 1u : 0u;
  }
  c += (stop < v) ? 1u : 0u;
  return c;
}

#define PI64 3.141592653589793

__device__ u32 dihedBin(V3 a, V3 b, V3 c, V3 d, double astep){
  V3 v1 = vsub(b, a), v2 = vsub(c, b), v3 = vsub(d, c);
  V3 n1 = vnorm(vcross(v1, v2));
  V3 n2 = vnorm(vcross(v2, v3));
  V3 m  = vcross(n1, n2);
  float dt = vdot(m, v2);
  float sg = (dt > 0.0f) ? 1.0f : ((dt < 0.0f) ? -1.0f : dt);
  float ss = sumsq3(m.x, m.y, m.z) + 1e-16f;
  float yy = sg * f32sqrt(ss);
  float xx = vdot(n1, n2);
  float th = atan2_cr(yy, xx);
  return binIdx64((double)th, astep, -PI64, PI64);
}

__device__ u32 bondBin(V3 a, V3 b, V3 c, double astep){
  V3 u = vnorm(vsub(b, a));
  V3 v = vnorm(vsub(c, a));
  V3 m = vcross(u, v);
  float ss = sumsq3(m.x, m.y, m.z) + 1e-16f;
  float yy = f32sqrt(ss);
  float xx = vdot(u, v);
  float th = atan2_cr(yy, xx);
  return binIdx64((double)th, astep, -PI64, PI64);
}

__device__ __forceinline__ float rlf(float v, int l){
  return __uint_as_float(__builtin_amdgcn_readlane(__float_as_uint(v), l));
}

// DPP full-wave sum on the VALU pipe (no DS ops): row_shr 1/2/4/8 within each
// row of 16, then row_bcast:15 (rows 1,3) and row_bcast:31 (rows 2,3);
// total lands in lane 63, broadcast via readlane. rocPRIM pattern.
template<int CTRL, int RMASK>
__device__ __forceinline__ float dpp_add(float x){
  int v = __builtin_amdgcn_update_dpp(0, __float_as_int(x), CTRL, RMASK, 0xf, true);
  return x + __int_as_float(v);
}
__device__ __forceinline__ float wave_sum63(float x){
  x = dpp_add<0x111, 0xf>(x);   // row_shr:1
  x = dpp_add<0x112, 0xf>(x);   // row_shr:2
  x = dpp_add<0x114, 0xf>(x);   // row_shr:4
  x = dpp_add<0x118, 0xf>(x);   // row_shr:8
  x = dpp_add<0x142, 0xa>(x);   // row_bcast:15 -> rows 1,3
  x = dpp_add<0x143, 0xc>(x);   // row_bcast:31 -> rows 2,3
  return __int_as_float(__builtin_amdgcn_readlane(__float_as_int(x), 63));
}

// ---- kernel A: W[128][316] f32 -> Wt[316][128] bf16 (RNE) ----
__global__ void prep_kernel(const float* __restrict__ W, u16* __restrict__ Wt){
  int e = blockIdx.x * 256 + threadIdx.x;
  if (e < FIN * DPAIR) {
    int d = e / FIN;
    int f = e - d * FIN;
    u32 u = __float_as_uint(W[e]);
    u32 r = (u + 0x7fffu + ((u >> 16) & 1u)) >> 16;
    Wt[f * DPAIR + d] = (u16)r;
  }
}

__global__ __launch_bounds__(NTHREAD, 4) void pairfeat_kernel(
    const float* __restrict__ mask, const float* __restrict__ cmask,
    const float* __restrict__ cnm, const float* __restrict__ crd,
    const float* __restrict__ W, const u16* __restrict__ Wt, const int useWt,
    const float* __restrict__ bias, const float* __restrict__ gam,
    const float* __restrict__ bet, float* __restrict__ out)
{
  __shared__ u32 Wl[FIN * 64];   // [f][d] bf16 pairs packed as u32: 80,896 B

  if (useWt) {
    const u32* src = (const u32*)Wt;
    for (int e = threadIdx.x; e < FIN * 64; e += NTHREAD) Wl[e] = src[e];
  } else {
    for (int e = threadIdx.x; e < FIN * DPAIR; e += NTHREAD) {
      int d = e & 127, f = e >> 7;
      u32 u = __float_as_uint(W[d * FIN + f]);
      u32 r = (u + 0x7fffu + ((u >> 16) & 1u)) >> 16;
      ((u16*)Wl)[f * DPAIR + d] = (u16)r;
    }
  }
  __syncthreads();

  const int lane = threadIdx.x & 63;
  const int gw = (blockIdx.x * NTHREAD + threadIdx.x) >> 6;
  const int d0 = lane << 1;
  const float2 bv = *(const float2*)(bias + d0);
  const float2 gv = *(const float2*)(gam + d0);
  const float2 ev = *(const float2*)(bet + d0);

  const double DSTEP  = (2.0 - 0.1) / 19.0;
  const double DSTART = 0.1, DSTOP = 2.0;
  const double ASTEP  = (PI64 + PI64) / 19.0;

  for (int ch = gw; ch < NCHUNK; ch += NWAVES) {
    const int i = ch / 12;
    const int j = (ch - i * 12) * 64 + lane;

    // ----- phase 1: per-lane pair (i, j) bins + weights (r12 numerics) -----
    float mi = mask[i], mj = mask[j];
    float hci = cmask[i * 4 + 3], hcj = cmask[j * 4 + 3];
    float pm = mi * mj;

    const float4* jq = (const float4*)(cnm + (size_t)j * 12);
    float4 q0 = jq[0], q1 = jq[1], q2 = jq[2];
    float cax = cnm[i*12+3], cay = cnm[i*12+4], caz = cnm[i*12+5];

    int sepb = i - j + 63;
    sepb = sepb < 0 ? 0 : (sepb > 126 ? 126 : sepb);
    u32 pack0 = (u32)sepb;
    {
      float ax[4] = {q0.x, q0.w, q1.z, q2.y};
      float ay[4] = {q0.y, q1.x, q1.w, q2.z};
      float az[4] = {q0.z, q1.y, q2.x, q2.w};
      int sh = 7;
#pragma unroll
      for (int a = 0; a < 4; ++a) {
        float dx = cax - ax[a];
        float dy = cay - ay[a];
        float dz = caz - az[a];
        float ss = sumsq3(dx, dy, dz) + 1e-10f;
        float dist = f32sqrt(ss);
        pack0 |= binIdx64((double)dist, DSTEP, DSTART, DSTOP) << sh; sh += 5;
      }
    }

    const float4* jr = (const float4*)(crd + (size_t)j * 12);
    float4 r0 = jr[0], r1 = jr[1], r2 = jr[2];
    V3 Nj  = {r0.x, r0.y, r0.z};
    V3 CAj = {r0.w, r1.x, r1.y};
    V3 CBj = {r2.y, r2.z, r2.w};
    V3 Ni  = {crd[i*12+0], crd[i*12+1], crd[i*12+2]};
    V3 CAi = {crd[i*12+3], crd[i*12+4], crd[i*12+5]};
    V3 CBi = {crd[i*12+9], crd[i*12+10], crd[i*12+11]};

    u32 pack1 = 0;
    pack1 |= dihedBin(Ni, CAi, CBi, CBj, ASTEP);
    pack1 |= dihedBin(Nj, CAj, CBj, CBi, ASTEP) << 5;
    pack1 |= bondBin(CAi, CBi, CBj, ASTEP) << 10;
    pack1 |= bondBin(CAj, CBj, CBi, ASTEP) << 15;
    pack1 |= dihedBin(CAi, CBi, CBj, CAj, ASTEP) << 20;

    float pm2 = pm * pm;
    float wbb = pm2;
    float wbb3 = pm2 * hcj;
    float tw = pm * hci; tw = tw * hci; float wor = tw * pm;

    // ----- phase 2: 64 pairs; gather + DPP-reduce LN + store -----
    float* ob = out + (size_t)ch * (64 * DPAIR);
#pragma unroll 2
    for (int p = 0; p < 64; ++p) {
      u32 k0 = __builtin_amdgcn_readlane(pack0, p);
      u32 k1 = __builtin_amdgcn_readlane(pack1, p);
      float Pm  = rlf(pm, p);
      float Wbb = rlf(wbb, p);
      float Wb3 = rlf(wbb3, p);
      float Wor = rlf(wor, p);

      float a0 = bv.x, a1 = bv.y;
      u32 cidx[10];
      cidx[0] = (k0 & 127u);
      cidx[1] = 127u +        ((k0 >> 7)  & 31u);
      cidx[2] = 127u + 21u +  ((k0 >> 12) & 31u);
      cidx[3] = 127u + 42u +  ((k0 >> 17) & 31u);
      cidx[4] = 127u + 63u +  ((k0 >> 22) & 31u);
      cidx[5] = 211u +        (k1 & 31u);
      cidx[6] = 211u + 21u +  ((k1 >> 5)  & 31u);
      cidx[7] = 211u + 42u +  ((k1 >> 10) & 31u);
      cidx[8] = 211u + 63u +  ((k1 >> 15) & 31u);
      cidx[9] = 211u + 84u +  ((k1 >> 20) & 31u);
      float wv[10] = {Pm, Wbb, Wbb, Wbb, Wb3, Wor, Wor, Wor, Wor, Wor};
#pragma unroll
      for (int t = 0; t < 10; ++t) {
        u32 u = Wl[cidx[t] * 64 + lane];
        a0 = fmaf(wv[t], __uint_as_float(u << 16), a0);
        a1 = fmaf(wv[t], __uint_as_float(u & 0xffff0000u), a1);
      }
      float s  = wave_sum63(a0 + a1);
      float s2 = wave_sum63(fmaf(a0, a0, a1 * a1));
      float mu = s * 0.0078125f;
      float var = fmaf(s2, 0.0078125f, -(mu * mu));
      float inv = 1.0f / sqrtf(var + 1e-5f);
      float o0 = (a0 - mu) * inv; o0 = fmaf(o0, gv.x, ev.x); o0 *= Pm;
      float o1 = (a1 - mu) * inv; o1 = fmaf(o1, gv.y, ev.y); o1 *= Pm;
      float2 ov; ov.x = o0; ov.y = o1;
      *(float2*)(ob + (size_t)p * DPAIR + d0) = ov;
    }
  }
}

extern "C" void kernel_launch(void* const* d_in, const int* in_sizes, int n_in,
                              void* d_out, int out_size, void* d_ws, size_t ws_size,
                              hipStream_t stream) {
  const float* mask  = (const float*)d_in[0];
  const float* cmask = (const float*)d_in[1];
  const float* cnm   = (const float*)d_in[2];
  const float* crd   = (const float*)d_in[3];
  const float* W     = (const float*)d_in[4];
  const float* bias  = (const float*)d_in[5];
  const float* gam   = (const float*)d_in[6];
  const float* bet   = (const float*)d_in[7];
  float* out = (float*)d_out;

  const size_t wtBytes = (size_t)FIN * DPAIR * sizeof(u16);
  int useWt = (ws_size >= wtBytes) ? 1 : 0;
  u16* Wt = (u16*)d_ws;
  if (useWt) {
    prep_kernel<<<(FIN * DPAIR + 255) / 256, 256, 0, stream>>>(W, Wt);
  }
  pairfeat_kernel<<<NBLOCK, NTHREAD, 0, stream>>>(
      mask, cmask, cnm, crd, W, Wt, useWt, bias, gam, bet, out);
}

// Round 15
// 155.787 us; speedup vs baseline: 1.2643x; 1.0906x over previous
//
#include <hip/hip_runtime.h>
#include <hip/hip_bf16.h>
#include <math.h>

#pragma clang fp contract(off)

#define NRES 768
#define FIN 316
#define DPAIR 128
#define NCHUNK 9216   // 768*768/64 pairs per chunk of 64
#define NBLOCK 512
#define NTHREAD 512
#define NWAVES (NBLOCK * (NTHREAD/64))

typedef unsigned int u32;
typedef unsigned short u16;

// f32 div/sqrt via f64: correctly rounded
__device__ __forceinline__ float f32div(float a, float b){ return (float)((double)a / (double)b); }
__device__ __forceinline__ float f32sqrt(float a){ return (float)sqrt((double)a); }

struct V3 { float x, y, z; };

__device__ __forceinline__ V3 vsub(const V3 a, const V3 b){
  V3 r; r.x = a.x - b.x; r.y = a.y - b.y; r.z = a.z - b.z; return r;
}
__device__ __forceinline__ V3 vcross(const V3 a, const V3 b){
  V3 r;
  r.x = a.y*b.z - a.z*b.y;
  r.y = a.z*b.x - a.x*b.z;
  r.z = a.x*b.y - a.y*b.x;
  return r;
}
// init-0 reduce (verified): 0+e0+e1+e2 — -0 normalization matches gold's diagonal.
__device__ __forceinline__ float vdot(const V3 a, const V3 b){
  float s = 0.0f + a.x*b.x;
  s = s + a.y*b.y;
  s = s + a.z*b.z;
  return s;
}
__device__ __forceinline__ float sumsq3(float x, float y, float z){
  float s = 0.0f + x*x;
  s = s + y*y;
  s = s + z*z;
  return s;
}
__device__ __forceinline__ V3 vnorm(const V3 v){
  float ss = sumsq3(v.x, v.y, v.z) + 1e-16f;
  float r = f32sqrt(ss);
  float c = fmaxf(r, 1e-8f);
  V3 o; o.x = f32div(v.x, c); o.y = f32div(v.y, c); o.z = f32div(v.z, c); return o;
}

// CR f32 atan2 (r12-verified gold flavor): explicit IEEE zero cases + f64 promote.
__device__ __forceinline__ float atan2_cr(float y, float x){
  if (y == 0.0f) {
    bool xneg = (__float_as_uint(x) >> 31) != 0;
    float pi_f = __uint_as_float(0x40490fdb);
    if (xneg) return (__float_as_uint(y) >> 31) ? -pi_f : pi_f;
    return y;
  }
  if (x == 0.0f) {
    float pio2 = __uint_as_float(0x3fc90fdb);
    return (y > 0.0f) ? pio2 : -pio2;
  }
  return (float)atan2((double)y, (double)x);
}

// numpy float64 linspace binning (r12-verified)
__device__ __forceinline__ u32 binIdx64(double v, double step, double start, double stop){
  u32 c = 0;
#pragma unroll
  for (int k = 0; k < 19; ++k){
    double lim = (double)k * step + start;
    c += (lim < v) ? 1u : 0u;
  }
  c += (stop < v) ? 1u : 0u;
  return c;
}

#define PI64 3.141592653589793

__device__ u32 dihedBin(V3 a, V3 b, V3 c, V3 d, double astep){
  V3 v1 = vsub(b, a), v2 = vsub(c, b), v3 = vsub(d, c);
  V3 n1 = vnorm(vcross(v1, v2));
  V3 n2 = vnorm(vcross(v2, v3));
  V3 m  = vcross(n1, n2);
  float dt = vdot(m, v2);
  float sg = (dt > 0.0f) ? 1.0f : ((dt < 0.0f) ? -1.0f : dt);
  float ss = sumsq3(m.x, m.y, m.z) + 1e-16f;
  float yy = sg * f32sqrt(ss);
  float xx = vdot(n1, n2);
  float th = atan2_cr(yy, xx);
  return binIdx64((double)th, astep, -PI64, PI64);
}

__device__ u32 bondBin(V3 a, V3 b, V3 c, double astep){
  V3 u = vnorm(vsub(b, a));
  V3 v = vnorm(vsub(c, a));
  V3 m = vcross(u, v);
  float ss = sumsq3(m.x, m.y, m.z) + 1e-16f;
  float yy = f32sqrt(ss);
  float xx = vdot(u, v);
  float th = atan2_cr(yy, xx);
  return binIdx64((double)th, astep, -PI64, PI64);
}

__device__ __forceinline__ float rlf(float v, int l){
  return __uint_as_float(__builtin_amdgcn_readlane(__float_as_uint(v), l));
}

// Half-wave DPP sum: after 5 stages, lane 31 = sum(lanes 0..31),
// lane 63 = sum(lanes 32..63). rocPRIM pattern minus the final bcast:31.
template<int CTRL, int RMASK>
__device__ __forceinline__ float dpp_add(float x){
  int v = __builtin_amdgcn_update_dpp(0, __float_as_int(x), CTRL, RMASK, 0xf, true);
  return x + __int_as_float(v);
}
__device__ __forceinline__ float halfwave_sum(float x){
  x = dpp_add<0x111, 0xf>(x);   // row_shr:1
  x = dpp_add<0x112, 0xf>(x);   // row_shr:2
  x = dpp_add<0x114, 0xf>(x);   // row_shr:4
  x = dpp_add<0x118, 0xf>(x);   // row_shr:8
  x = dpp_add<0x142, 0xa>(x);   // row_bcast:15 -> rows 1,3
  return x;                     // lane31 / lane63 hold the half sums
}

// ---- kernel A: W[128][316] f32 -> Wt[316][128] bf16 (RNE) ----
__global__ void prep_kernel(const float* __restrict__ W, u16* __restrict__ Wt){
  int e = blockIdx.x * 256 + threadIdx.x;
  if (e < FIN * DPAIR) {
    int d = e / FIN;
    int f = e - d * FIN;
    u32 u = __float_as_uint(W[e]);
    u32 r = (u + 0x7fffu + ((u >> 16) & 1u)) >> 16;
    Wt[f * DPAIR + d] = (u16)r;
  }
}

__global__ __launch_bounds__(NTHREAD, 4) void pairfeat_kernel(
    const float* __restrict__ mask, const float* __restrict__ cmask,
    const float* __restrict__ cnm, const float* __restrict__ crd,
    const float* __restrict__ W, const u16* __restrict__ Wt, const int useWt,
    const float* __restrict__ bias, const float* __restrict__ gam,
    const float* __restrict__ bet, float* __restrict__ out)
{
  __shared__ u32 Wl[FIN * 64];   // [f][d-pair] bf16 pairs packed as u32: 80,896 B

  if (useWt) {
    const u32* src = (const u32*)Wt;
    for (int e = threadIdx.x; e < FIN * 64; e += NTHREAD) Wl[e] = src[e];
  } else {
    for (int e = threadIdx.x; e < FIN * DPAIR; e += NTHREAD) {
      int d = e & 127, f = e >> 7;
      u32 u = __float_as_uint(W[d * FIN + f]);
      u32 r = (u + 0x7fffu + ((u >> 16) & 1u)) >> 16;
      ((u16*)Wl)[f * DPAIR + d] = (u16)r;
    }
  }
  __syncthreads();

  const int lane = threadIdx.x & 63;
  const int gw = (blockIdx.x * NTHREAD + threadIdx.x) >> 6;
  const int l5 = lane & 31;          // dim-group index within half-wave
  const int h  = lane >> 5;          // 0: even pair, 1: odd pair
  const int dbase = l5 * 4;          // this lane's 4 dims
  const float4 bv = *(const float4*)(bias + dbase);
  const float4 gv = *(const float4*)(gam + dbase);
  const float4 ev = *(const float4*)(bet + dbase);

  const double DSTEP  = (2.0 - 0.1) / 19.0;
  const double DSTART = 0.1, DSTOP = 2.0;
  const double ASTEP  = (PI64 + PI64) / 19.0;

  for (int ch = gw; ch < NCHUNK; ch += NWAVES) {
    const int i = ch / 12;
    const int j = (ch - i * 12) * 64 + lane;

    // ----- phase 1: per-lane pair (i, j) bins + weights (r12 numerics) -----
    float mi = mask[i], mj = mask[j];
    float hci = cmask[i * 4 + 3], hcj = cmask[j * 4 + 3];
    float pm = mi * mj;

    const float4* jq = (const float4*)(cnm + (size_t)j * 12);
    float4 q0 = jq[0], q1 = jq[1], q2 = jq[2];
    float cax = cnm[i*12+3], cay = cnm[i*12+4], caz = cnm[i*12+5];

    int sepb = i - j + 63;
    sepb = sepb < 0 ? 0 : (sepb > 126 ? 126 : sepb);
    u32 pack0 = (u32)sepb;
    {
      float ax[4] = {q0.x, q0.w, q1.z, q2.y};
      float ay[4] = {q0.y, q1.x, q1.w, q2.z};
      float az[4] = {q0.z, q1.y, q2.x, q2.w};
      int sh = 7;
#pragma unroll
      for (int a = 0; a < 4; ++a) {
        float dx = cax - ax[a];
        float dy = cay - ay[a];
        float dz = caz - az[a];
        float ss = sumsq3(dx, dy, dz) + 1e-10f;
        float dist = f32sqrt(ss);
        pack0 |= binIdx64((double)dist, DSTEP, DSTART, DSTOP) << sh; sh += 5;
      }
    }

    const float4* jr = (const float4*)(crd + (size_t)j * 12);
    float4 r0 = jr[0], r1 = jr[1], r2 = jr[2];
    V3 Nj  = {r0.x, r0.y, r0.z};
    V3 CAj = {r0.w, r1.x, r1.y};
    V3 CBj = {r2.y, r2.z, r2.w};
    V3 Ni  = {crd[i*12+0], crd[i*12+1], crd[i*12+2]};
    V3 CAi = {crd[i*12+3], crd[i*12+4], crd[i*12+5]};
    V3 CBi = {crd[i*12+9], crd[i*12+10], crd[i*12+11]};

    u32 pack1 = 0;
    pack1 |= dihedBin(Ni, CAi, CBi, CBj, ASTEP);
    pack1 |= dihedBin(Nj, CAj, CBj, CBi, ASTEP) << 5;
    pack1 |= bondBin(CAi, CBi, CBj, ASTEP) << 10;
    pack1 |= bondBin(CAj, CBj, CBi, ASTEP) << 15;
    pack1 |= dihedBin(CAi, CBi, CBj, CAj, ASTEP) << 20;

    float pm2 = pm * pm;
    float wbb = pm2;
    float wbb3 = pm2 * hcj;
    float tw = pm * hci; tw = tw * hci; float wor = tw * pm;

    // ----- phase 2: 2 pairs per iteration; half-wave per pair -----
    float* ob = out + (size_t)ch * (64 * DPAIR);
#pragma unroll 2
    for (int p = 0; p < 64; p += 2) {
      // broadcast both pairs' packs/weights, select by half
      u32 k0a = __builtin_amdgcn_readlane(pack0, p);
      u32 k0b = __builtin_amdgcn_readlane(pack0, p + 1);
      u32 k1a = __builtin_amdgcn_readlane(pack1, p);
      u32 k1b = __builtin_amdgcn_readlane(pack1, p + 1);
      u32 k0 = h ? k0b : k0a;
      u32 k1 = h ? k1b : k1a;
      float Pm  = h ? rlf(pm, p + 1)   : rlf(pm, p);
      float Wbb = h ? rlf(wbb, p + 1)  : rlf(wbb, p);
      float Wb3 = h ? rlf(wbb3, p + 1) : rlf(wbb3, p);
      float Wor = h ? rlf(wor, p + 1)  : rlf(wor, p);

      u32 cidx[10];
      cidx[0] = (k0 & 127u);
      cidx[1] = 127u +        ((k0 >> 7)  & 31u);
      cidx[2] = 127u + 21u +  ((k0 >> 12) & 31u);
      cidx[3] = 127u + 42u +  ((k0 >> 17) & 31u);
      cidx[4] = 127u + 63u +  ((k0 >> 22) & 31u);
      cidx[5] = 211u +        (k1 & 31u);
      cidx[6] = 211u + 21u +  ((k1 >> 5)  & 31u);
      cidx[7] = 211u + 42u +  ((k1 >> 10) & 31u);
      cidx[8] = 211u + 63u +  ((k1 >> 15) & 31u);
      cidx[9] = 211u + 84u +  ((k1 >> 20) & 31u);
      float wv[10] = {Pm, Wbb, Wbb, Wbb, Wb3, Wor, Wor, Wor, Wor, Wor};

      float a0 = bv.x, a1 = bv.y, a2 = bv.z, a3 = bv.w;
#pragma unroll
      for (int t = 0; t < 10; ++t) {
        uint2 u2 = *(const uint2*)&Wl[cidx[t] * 64 + l5 * 2];   // dims 4*l5..4*l5+3
        a0 = fmaf(wv[t], __uint_as_float(u2.x << 16), a0);
        a1 = fmaf(wv[t], __uint_as_float(u2.x & 0xffff0000u), a1);
        a2 = fmaf(wv[t], __uint_as_float(u2.y << 16), a2);
        a3 = fmaf(wv[t], __uint_as_float(u2.y & 0xffff0000u), a3);
      }
      float s  = halfwave_sum((a0 + a1) + (a2 + a3));
      float s2 = halfwave_sum(fmaf(a0, a0, a1 * a1) + fmaf(a2, a2, a3 * a3));
      float sSel  = h ? rlf(s, 63)  : rlf(s, 31);
      float s2Sel = h ? rlf(s2, 63) : rlf(s2, 31);
      float mu = sSel * 0.0078125f;
      float var = fmaf(s2Sel, 0.0078125f, -(mu * mu));
      float inv = 1.0f / sqrtf(var + 1e-5f);
      float4 ov;
      float o0 = (a0 - mu) * inv; ov.x = fmaf(o0, gv.x, ev.x) * Pm;
      float o1 = (a1 - mu) * inv; ov.y = fmaf(o1, gv.y, ev.y) * Pm;
      float o2 = (a2 - mu) * inv; ov.z = fmaf(o2, gv.z, ev.z) * Pm;
      float o3 = (a3 - mu) * inv; ov.w = fmaf(o3, gv.w, ev.w) * Pm;
      *(float4*)(ob + (size_t)(p + h) * DPAIR + dbase) = ov;
    }
  }
}

extern "C" void kernel_launch(void* const* d_in, const int* in_sizes, int n_in,
                              void* d_out, int out_size, void* d_ws, size_t ws_size,
                              hipStream_t stream) {
  const float* mask  = (const float*)d_in[0];
  const float* cmask = (const float*)d_in[1];
  const float* cnm   = (const float*)d_in[2];
  const float* crd   = (const float*)d_in[3];
  const float* W     = (const float*)d_in[4];
  const float* bias  = (const float*)d_in[5];
  const float* gam   = (const float*)d_in[6];
  const float* bet   = (const float*)d_in[7];
  float* out = (float*)d_out;

  const size_t wtBytes = (size_t)FIN * DPAIR * sizeof(u16);
  int useWt = (ws_size >= wtBytes) ? 1 : 0;
  u16* Wt = (u16*)d_ws;
  if (useWt) {
    prep_kernel<<<(FIN * DPAIR + 255) / 256, 256, 0, stream>>>(W, Wt);
  }
  pairfeat_kernel<<<NBLOCK, NTHREAD, 0, stream>>>(
      mask, cmask, cnm, crd, W, Wt, useWt, bias, gam, bet, out);
}